// Round 2
// baseline (203.809 us; speedup 1.0000x reference)
//
#include <hip/hip_runtime.h>

#define DEV_INLINE __device__ __forceinline__

// Native 16B vector type — __builtin_nontemporal_store requires a native
// clang ext-vector (HIP's float4 is a class and is rejected).
typedef float f32x4 __attribute__((ext_vector_type(4)));

// Numerically stable softplus: max(v,0) + log1p(exp(-|v|)).
DEV_INLINE float softplus_f(float v) {
    return fmaxf(v, 0.0f) + __logf(1.0f + __expf(-fabsf(v)));
}

// One thread = one row (token). Output staged through WAVE-PRIVATE LDS
// slices (9 KB per wave) so global stores are 1 KiB-contiguous per wave
// instruction, WITHOUT a block-wide __syncthreads(): the transpose exchange
// is intra-wave, so a s_waitcnt lgkmcnt(0) suffices. All 16 resident
// waves/CU proceed as independent compute->store pipelines (no barrier
// convoying of the store burst).
//
// Stores are non-temporal: the 151 MB output is written once and never
// re-read by this kernel, so bypass L2 write-allocate churn.
//
// LDS write phase: lane t, chunk m -> bank group 4*(t+m) mod 32: within each
// 16-lane b128 phase only 2-way aliasing -> free (m136). Read phase:
// lane-consecutive float4 slots -> conflict-free.
__global__ __launch_bounds__(256) void pb_kernel(
    const float* __restrict__ x,
    const float* __restrict__ W_in, const float* __restrict__ b_in,
    const float* __restrict__ W1,   const float* __restrict__ b1,
    const float* __restrict__ W2,   const float* __restrict__ b2,
    const float* __restrict__ W3,   const float* __restrict__ b3,
    const float* __restrict__ W4,   const float* __restrict__ b4,
    const float* __restrict__ W_out,const float* __restrict__ b_out,
    float* __restrict__ out, int n_rows)
{
    __shared__ f32x4 sbuf[256 * 9];   // 36 KB: 4 waves x (64 rows x 9 float4)

    const int tid  = threadIdx.x;
    const int lane = tid & 63;
    const int wv   = tid >> 6;

    const int row_raw = blockIdx.x * 256 + tid;
    const int row = row_raw < n_rows ? row_raw : n_rows - 1;  // clamp (grid exact anyway)

    // ---- load one row of x (6 floats, 24B stride -> three float2 loads) ----
    const float2* xv = (const float2*)(x + (size_t)row * 6);
    const float2 p0 = xv[0], p1 = xv[1], p2 = xv[2];
    const float xin[6] = { p0.x, p0.y, p1.x, p1.y, p2.x, p2.y };

    // ---- input layer 6 -> 8 ----
    float y[8];
    #pragma unroll
    for (int o = 0; o < 8; ++o) {
        float acc = b_in[o];
        #pragma unroll
        for (int i = 0; i < 6; ++i)
            acc = fmaf(W_in[o * 6 + i], xin[i], acc);
        y[o] = softplus_f(acc);
    }

    // ---- 4 hidden layers 8 -> 8 ----
    const float* Ws[4] = { W1, W2, W3, W4 };
    const float* bs[4] = { b1, b2, b3, b4 };
    #pragma unroll
    for (int l = 0; l < 4; ++l) {
        const float* __restrict__ W = Ws[l];
        const float* __restrict__ b = bs[l];
        float t[8];
        #pragma unroll
        for (int o = 0; o < 8; ++o) {
            float acc = b[o];
            #pragma unroll
            for (int i = 0; i < 8; ++i)
                acc = fmaf(W[o * 8 + i], y[i], acc);
            t[o] = softplus_f(acc);
        }
        #pragma unroll
        for (int o = 0; o < 8; ++o) y[o] = t[o];
    }

    // ---- output layer 8 -> 15 ----
    float u[15];
    #pragma unroll
    for (int o = 0; o < 15; ++o) {
        float acc = b_out[o];
        #pragma unroll
        for (int i = 0; i < 8; ++i)
            acc = fmaf(W_out[o * 8 + i], y[i], acc);
        u[o] = acc;
    }

    // ---- assemble antisymmetric 6x6 (fully unrolled -> folds into regs) ----
    float L[36];
    #pragma unroll
    for (int i = 0; i < 36; ++i) L[i] = 0.0f;
    {
        int k = 0;
        #pragma unroll
        for (int i = 0; i < 6; ++i) {
            #pragma unroll
            for (int j = i + 1; j < 6; ++j) {
                L[i * 6 + j] = u[k];
                L[j * 6 + i] = -u[k];
                ++k;
            }
        }
    }

    // ---- stage to this wave's private LDS slice (9 x ds_write_b128) ----
    f32x4* wbuf = sbuf + wv * (64 * 9);
    #pragma unroll
    for (int m = 0; m < 9; ++m) {
        f32x4 v;
        v.x = L[4 * m + 0]; v.y = L[4 * m + 1];
        v.z = L[4 * m + 2]; v.w = L[4 * m + 3];
        wbuf[lane * 9 + m] = v;
    }

    // Intra-wave exchange only: drain this wave's LDS writes. No block
    // barrier — waves proceed independently. "memory" clobber keeps the
    // compiler from hoisting the ds_reads above this point.
    asm volatile("s_waitcnt lgkmcnt(0)" ::: "memory");

    // ---- wave-coalesced non-temporal stores: 9 KB contiguous per wave ----
    const long long wave_f4 = ((long long)blockIdx.x * 256 + (wv << 6)) * 9;
    f32x4* __restrict__ dst = (f32x4*)out + wave_f4;
    const long long total_f4 = (long long)n_rows * 9;

    if (wave_f4 + 576 <= total_f4) {          // full wave (always, grid exact)
        #pragma unroll
        for (int q = 0; q < 9; ++q) {
            const int idx = q * 64 + lane;
            __builtin_nontemporal_store(wbuf[idx], dst + idx);
        }
    } else {                                   // tail safety (dead in practice)
        #pragma unroll
        for (int q = 0; q < 9; ++q) {
            const int idx = q * 64 + lane;
            if (wave_f4 + idx < total_f4)
                __builtin_nontemporal_store(wbuf[idx], dst + idx);
        }
    }
}

extern "C" void kernel_launch(void* const* d_in, const int* in_sizes, int n_in,
                              void* d_out, int out_size, void* d_ws, size_t ws_size,
                              hipStream_t stream) {
    const float* x     = (const float*)d_in[0];
    const float* W_in  = (const float*)d_in[1];
    const float* b_in  = (const float*)d_in[2];
    const float* W1    = (const float*)d_in[3];
    const float* b1    = (const float*)d_in[4];
    const float* W2    = (const float*)d_in[5];
    const float* b2    = (const float*)d_in[6];
    const float* W3    = (const float*)d_in[7];
    const float* b3    = (const float*)d_in[8];
    const float* W4    = (const float*)d_in[9];
    const float* b4    = (const float*)d_in[10];
    const float* W_out = (const float*)d_in[11];
    const float* b_out = (const float*)d_in[12];
    float* out = (float*)d_out;

    const int n_rows = in_sizes[0] / 6;           // B*T = 1,048,576
    const int block = 256;
    const int grid = (n_rows + block - 1) / block;

    hipLaunchKernelGGL(pb_kernel, dim3(grid), dim3(block), 0, stream,
                       x, W_in, b_in, W1, b1, W2, b2, W3, b3, W4, b4,
                       W_out, b_out, out, n_rows);
}